// Round 11
// baseline (348.135 us; speedup 1.0000x reference)
//
#include <hip/hip_runtime.h>
#include <hip/hip_bf16.h>
#include <math.h>

#define D_MODEL 1024
#define N_HEADS 16
#define D_HEAD  64
#define SEQ     2048
#define NBATCH  2
#define NROWS   (NBATCH * SEQ)      // 4096

#define C2F 0.18033688011112042f    // 0.125 * log2(e), folded into Q weights/bias

typedef __attribute__((ext_vector_type(8))) short short8v;        // 8 bf16
typedef __attribute__((ext_vector_type(4))) float f32x4;
typedef __attribute__((ext_vector_type(16))) float f32x16;
typedef __attribute__((ext_vector_type(4))) unsigned int u32x4;

__device__ __forceinline__ unsigned short f2bf(float x) {
    unsigned int u = __float_as_uint(x);
    return (unsigned short)((u + 0x7FFFu + ((u >> 16) & 1u)) >> 16);   // RNE
}
// truncation split: hi = top-16-bits of fp32, lo = RNE(x - hi)
__device__ __forceinline__ void split_bf(float x, unsigned short& hi, unsigned short& lo) {
    unsigned int u = __float_as_uint(x);
    unsigned int ht = u & 0xFFFF0000u;
    hi = (unsigned short)(ht >> 16);
    lo = f2bf(x - __uint_as_float(ht));
}
// packed RNE f32x2 -> bf16x2
__device__ __forceinline__ unsigned int cvtpk(float lo, float hi) {
    unsigned int r;
    asm("v_cvt_pk_bf16_f32 %0, %1, %2" : "=v"(r) : "v"(lo), "v"(hi));
    return r;
}
__device__ __forceinline__ short8v u2s(u32x4 v) {
    union { u32x4 u; short8v s; } c; c.u = v; return c.s;
}

// ---------------------------------------------------------------------------
// Zero-fill (float4 granularity) — initializes Obuf+lbuf each launch.
// ---------------------------------------------------------------------------
__global__ __launch_bounds__(256) void zero_kernel(float4* p, int n4)
{
    const int i = blockIdx.x * 256 + threadIdx.x;
    if (i < n4) p[i] = make_float4(0.f, 0.f, 0.f, 0.f);
}

// ---------------------------------------------------------------------------
// Weight transpose + split: W[K][N] fp32 -> Th[N][K] (+ Tl[N][K] if write_lo).
// Columns n < qcols pre-scaled by C2F. write_lo=0 -> Th is RNE-rounded.
// ---------------------------------------------------------------------------
__global__ __launch_bounds__(256) void splitT_kernel(
    const float* __restrict__ W, unsigned short* __restrict__ Th,
    unsigned short* __restrict__ Tl, int K, int N, int qcols, int write_lo)
{
    __shared__ float tile[64][68];
    const int tid = threadIdx.x;
    const int nbn = N >> 6;
    const int k0 = (blockIdx.x / nbn) << 6;
    const int n0 = (blockIdx.x % nbn) << 6;
    const int r  = tid >> 4;
    const int c4 = (tid & 15) * 4;

#pragma unroll
    for (int i = 0; i < 4; ++i) {
        float4 v = *(const float4*)(W + (size_t)(k0 + r + i * 16) * N + n0 + c4);
        *(float4*)&tile[r + i * 16][c4] = v;
    }
    __syncthreads();

    const int kl = (tid & 15) * 4;
#pragma unroll
    for (int i = 0; i < 4; ++i) {
        const int nl = (tid >> 4) + i * 16;
        const float sc = (n0 + nl < qcols) ? C2F : 1.0f;
        if (write_lo) {
            ushort4 h4, l4;
            unsigned short h, l;
            split_bf(tile[kl + 0][nl] * sc, h, l); h4.x = h; l4.x = l;
            split_bf(tile[kl + 1][nl] * sc, h, l); h4.y = h; l4.y = l;
            split_bf(tile[kl + 2][nl] * sc, h, l); h4.z = h; l4.z = l;
            split_bf(tile[kl + 3][nl] * sc, h, l); h4.w = h; l4.w = l;
            *(ushort4*)(Th + (size_t)(n0 + nl) * K + k0 + kl) = h4;
            *(ushort4*)(Tl + (size_t)(n0 + nl) * K + k0 + kl) = l4;
        } else {
            ushort4 h4;
            h4.x = f2bf(tile[kl + 0][nl] * sc);
            h4.y = f2bf(tile[kl + 1][nl] * sc);
            h4.z = f2bf(tile[kl + 2][nl] * sc);
            h4.w = f2bf(tile[kl + 3][nl] * sc);
            *(ushort4*)(Th + (size_t)(n0 + nl) * K + k0 + kl) = h4;
        }
    }
}

// ---------------------------------------------------------------------------
// GEMM1 (1-term bf16): qkv[M,N](bf16) = RNE_bf16(A) @ Bh[N,K]^T + bias.
// Software-pipelined (T14 rotation).
// ---------------------------------------------------------------------------
#define ASTRIDE 40    // bf16 elems; 80B row stride

__global__ __launch_bounds__(256) void gemm_xw_kernel(
    const float* __restrict__ A,
    const unsigned short* __restrict__ Bth,
    const float* __restrict__ bias,
    unsigned short* __restrict__ C, int M, int N, int K, int qcols)
{
    __shared__ __align__(16) unsigned short Ab[128][ASTRIDE];
    __shared__ __align__(16) unsigned short Bh[128][ASTRIDE];

    const int tid  = threadIdx.x;
    const int wave = tid >> 6;
    const int lane = tid & 63;
    const int col  = lane & 15;
    const int q4   = lane >> 4;
    const int wm   = (wave >> 1) * 64;
    const int wn   = (wave & 1) * 64;

    const int nwg = gridDim.x;
    const int cpx = nwg >> 3;
    const int swz = (blockIdx.x & 7) * cpx + (blockIdx.x >> 3);
    const int nbn = N / 128;
    const int bm = (swz / nbn) * 128;
    const int bn = (swz % nbn) * 128;

    const int sr = tid >> 1;
    const int sq = (tid & 1) * 16;
    const float* aptr = A + (size_t)(bm + sr) * K + sq;
    const unsigned short* bhp = Bth + (size_t)(bn + sr) * K + sq;

    f32x4 acc[4][4];
#pragma unroll
    for (int i = 0; i < 4; ++i)
#pragma unroll
        for (int j = 0; j < 4; ++j) acc[i][j] = (f32x4){0.f, 0.f, 0.f, 0.f};

    float4 a0, a1, a2, a3;
    short8v b0h, b1h;

#define G1LOAD(k0) { \
    a0 = *(const float4*)(aptr + (k0)); \
    a1 = *(const float4*)(aptr + (k0) + 4); \
    a2 = *(const float4*)(aptr + (k0) + 8); \
    a3 = *(const float4*)(aptr + (k0) + 12); \
    b0h = *(const short8v*)(bhp + (k0)); \
    b1h = *(const short8v*)(bhp + (k0) + 8); \
}

#define G1WRITE() { \
    u32x4 p0, p1; \
    p0.x = cvtpk(a0.x, a0.y); p0.y = cvtpk(a0.z, a0.w); \
    p0.z = cvtpk(a1.x, a1.y); p0.w = cvtpk(a1.z, a1.w); \
    p1.x = cvtpk(a2.x, a2.y); p1.y = cvtpk(a2.z, a2.w); \
    p1.z = cvtpk(a3.x, a3.y); p1.w = cvtpk(a3.z, a3.w); \
    *(u32x4*)&Ab[sr][sq]     = p0; \
    *(u32x4*)&Ab[sr][sq + 8] = p1; \
    *(short8v*)&Bh[sr][sq]     = b0h; \
    *(short8v*)&Bh[sr][sq + 8] = b1h; \
}

#define G1COMP() { \
    short8v af[4]; \
    _Pragma("unroll") \
    for (int mt = 0; mt < 4; ++mt) \
        af[mt] = *(const short8v*)&Ab[wm + mt * 16 + col][q4 * 8]; \
    _Pragma("unroll") \
    for (int nt = 0; nt < 4; ++nt) { \
        short8v bhf = *(const short8v*)&Bh[wn + nt * 16 + col][q4 * 8]; \
        _Pragma("unroll") \
        for (int mt = 0; mt < 4; ++mt) \
            acc[mt][nt] = __builtin_amdgcn_mfma_f32_16x16x32_bf16(af[mt], bhf, acc[mt][nt], 0, 0, 0); \
    } \
}

    G1LOAD(0);
    G1WRITE();
    for (int k0 = 32; k0 < K; k0 += 32) {
        G1LOAD(k0);
        __syncthreads();
        G1COMP();
        __syncthreads();
        G1WRITE();
    }
    __syncthreads();
    G1COMP();
#undef G1LOAD
#undef G1WRITE
#undef G1COMP

    const float bscale = (bn < qcols) ? C2F : 1.0f;
    float bv[4];
#pragma unroll
    for (int nt = 0; nt < 4; ++nt) bv[nt] = bias[bn + wn + nt * 16 + col] * bscale;

#pragma unroll
    for (int mt = 0; mt < 4; ++mt)
#pragma unroll
        for (int r = 0; r < 4; ++r) {
            const int row = bm + wm + mt * 16 + q4 * 4 + r;
#pragma unroll
            for (int nt = 0; nt < 4; ++nt)
                C[(size_t)row * N + bn + wn + nt * 16 + col] = f2bf(acc[mt][nt][r] + bv[nt]);
        }
}

// ---------------------------------------------------------------------------
// GEMM2: out[M,N](fp32) = (Aoh+Aol)[M,K] @ (Bh+Bl)[N,K]^T + bias, 3-term.
// ---------------------------------------------------------------------------
__global__ __launch_bounds__(256) void gemm_ao_kernel(
    const unsigned short* __restrict__ Aoh,
    const unsigned short* __restrict__ Aol,
    const unsigned short* __restrict__ Bth,
    const unsigned short* __restrict__ Btl,
    const float* __restrict__ bias,
    float* __restrict__ C, int M, int N, int K)
{
    __shared__ __align__(16) unsigned short Ah[128][ASTRIDE];
    __shared__ __align__(16) unsigned short Al[128][ASTRIDE];
    __shared__ __align__(16) unsigned short Bh[128][ASTRIDE];
    __shared__ __align__(16) unsigned short Bl[128][ASTRIDE];

    const int tid  = threadIdx.x;
    const int wave = tid >> 6;
    const int lane = tid & 63;
    const int col  = lane & 15;
    const int q4   = lane >> 4;
    const int wm   = (wave >> 1) * 64;
    const int wn   = (wave & 1) * 64;

    const int nwg = gridDim.x;
    const int cpx = nwg >> 3;
    const int swz = (blockIdx.x & 7) * cpx + (blockIdx.x >> 3);
    const int nbn = N / 128;
    const int bm = (swz / nbn) * 128;
    const int bn = (swz % nbn) * 128;

    const int sr = tid >> 1;
    const int sq = (tid & 1) * 16;
    const unsigned short* ahp = Aoh + (size_t)(bm + sr) * K + sq;
    const unsigned short* alp = Aol + (size_t)(bm + sr) * K + sq;
    const unsigned short* bhp = Bth + (size_t)(bn + sr) * K + sq;
    const unsigned short* blp = Btl + (size_t)(bn + sr) * K + sq;

    f32x4 acc[4][4];
#pragma unroll
    for (int i = 0; i < 4; ++i)
#pragma unroll
        for (int j = 0; j < 4; ++j) acc[i][j] = (f32x4){0.f, 0.f, 0.f, 0.f};

    short8v a0h, a1h, a0l, a1l, b0h, b1h, b0l, b1l;

#define G2LOAD(k0) { \
    a0h = *(const short8v*)(ahp + (k0)); \
    a1h = *(const short8v*)(ahp + (k0) + 8); \
    a0l = *(const short8v*)(alp + (k0)); \
    a1l = *(const short8v*)(alp + (k0) + 8); \
    b0h = *(const short8v*)(bhp + (k0)); \
    b1h = *(const short8v*)(bhp + (k0) + 8); \
    b0l = *(const short8v*)(blp + (k0)); \
    b1l = *(const short8v*)(blp + (k0) + 8); \
}

#define G2WRITE() { \
    *(short8v*)&Ah[sr][sq]     = a0h; \
    *(short8v*)&Ah[sr][sq + 8] = a1h; \
    *(short8v*)&Al[sr][sq]     = a0l; \
    *(short8v*)&Al[sr][sq + 8] = a1l; \
    *(short8v*)&Bh[sr][sq]     = b0h; \
    *(short8v*)&Bh[sr][sq + 8] = b1h; \
    *(short8v*)&Bl[sr][sq]     = b0l; \
    *(short8v*)&Bl[sr][sq + 8] = b1l; \
}

#define G2COMP() { \
    short8v ahf[4], alf[4]; \
    _Pragma("unroll") \
    for (int mt = 0; mt < 4; ++mt) { \
        ahf[mt] = *(const short8v*)&Ah[wm + mt * 16 + col][q4 * 8]; \
        alf[mt] = *(const short8v*)&Al[wm + mt * 16 + col][q4 * 8]; \
    } \
    _Pragma("unroll") \
    for (int nt = 0; nt < 4; ++nt) { \
        short8v bhf = *(const short8v*)&Bh[wn + nt * 16 + col][q4 * 8]; \
        short8v blf = *(const short8v*)&Bl[wn + nt * 16 + col][q4 * 8]; \
        _Pragma("unroll") \
        for (int mt = 0; mt < 4; ++mt) { \
            acc[mt][nt] = __builtin_amdgcn_mfma_f32_16x16x32_bf16(ahf[mt], bhf, acc[mt][nt], 0, 0, 0); \
            acc[mt][nt] = __builtin_amdgcn_mfma_f32_16x16x32_bf16(alf[mt], bhf, acc[mt][nt], 0, 0, 0); \
            acc[mt][nt] = __builtin_amdgcn_mfma_f32_16x16x32_bf16(ahf[mt], blf, acc[mt][nt], 0, 0, 0); \
        } \
    } \
}

    G2LOAD(0);
    G2WRITE();
    for (int k0 = 32; k0 < K; k0 += 32) {
        G2LOAD(k0);
        __syncthreads();
        G2COMP();
        __syncthreads();
        G2WRITE();
    }
    __syncthreads();
    G2COMP();
#undef G2LOAD
#undef G2WRITE
#undef G2COMP

    float bv[4];
#pragma unroll
    for (int nt = 0; nt < 4; ++nt) bv[nt] = bias[bn + wn + nt * 16 + col];

#pragma unroll
    for (int mt = 0; mt < 4; ++mt)
#pragma unroll
        for (int r = 0; r < 4; ++r) {
            const int row = bm + wm + mt * 16 + q4 * 4 + r;
#pragma unroll
            for (int nt = 0; nt < 4; ++nt)
                C[(size_t)row * N + bn + wn + nt * 16 + col] = acc[mt][nt][r] + bv[nt];
        }
}

// ---------------------------------------------------------------------------
// MFMA flash attention (R10 data path), inter-block K-split x2 (blockIdx.z).
// Fixed-max softmax => partials combine exactly by summation: each block
// atomicAdds its partial O^T (fp32) and l into zeroed global buffers.
// Exactly 2 commutative fp32 adds per address -> bit-deterministic.
// ---------------------------------------------------------------------------
__global__ __launch_bounds__(128) void attn_mfma_kernel(
    const unsigned short* __restrict__ qkv,
    float* __restrict__ Obuf, float* __restrict__ lbuf)
{
    __shared__ __align__(16) unsigned short Ks[64 * 64];   // [key][dim] swizzled
    __shared__ __align__(16) unsigned short Vt[64 * 64];   // [dim][key] swizzled

    const int tid  = threadIdx.x;
    const int wave = tid >> 6;
    const int lane = tid & 63;
    const int l31  = lane & 31;
    const int lh   = lane >> 5;
    const bool hihalf = (lh != 0);

    const int bh = blockIdx.x;           // b*16 + h
    const int qt = blockIdx.y;           // 0..31
    const int ksplit = blockIdx.z;       // 0..1 : which 1024-key half
    const int b = bh >> 4;
    const int h = bh & 15;
    const int qrow0 = b * SEQ + qt * 64 + wave * 32;
    const int krow0 = b * SEQ + ksplit * 1024;

    // Q fragments (B-operand), pre-scaled by C2F in GEMM1
    short8v qf[4];
    {
        const unsigned short* qsrc = qkv + (size_t)(qrow0 + l31) * (3 * D_MODEL) + h * 64 + lh * 8;
#pragma unroll
        for (int s = 0; s < 4; ++s)
            qf[s] = *(const short8v*)(qsrc + s * 16);
    }

    // staging indices (128 threads)
    const int krow  = tid >> 1;          // 0..63
    const int khalf = (tid & 1) * 32;    // elems (64 B half-row)
    const int vk0   = (tid & 15) * 4;    // 4 keys
    const int vd0   = (tid >> 4) * 8;    // 8 dims

    f32x16 ot0, ot1;
#pragma unroll
    for (int r = 0; r < 16; ++r) { ot0[r] = 0.f; ot1[r] = 0.f; }
    float ll = 0.f;

    short8v kg[4], vg[4];
    const int swr = (lane & 7) << 3;

#define ALOAD(c) { \
    const unsigned short* ksrc = qkv + (size_t)(krow0 + (c) * 64 + krow) * (3 * D_MODEL) \
                                 + D_MODEL + h * 64 + khalf; \
    kg[0] = ((const short8v*)ksrc)[0]; \
    kg[1] = ((const short8v*)ksrc)[1]; \
    kg[2] = ((const short8v*)ksrc)[2]; \
    kg[3] = ((const short8v*)ksrc)[3]; \
    _Pragma("unroll") \
    for (int i2 = 0; i2 < 4; ++i2) \
        vg[i2] = *(const short8v*)(qkv + (size_t)(krow0 + (c) * 64 + vk0 + i2) * (3 * D_MODEL) \
                                   + 2 * D_MODEL + h * 64 + vd0); \
}

#define AWRITE() { \
    const int base = krow * 64 + khalf; \
    const int sw = (krow & 7) << 3; \
    *(short8v*)&Ks[(base)      ^ sw] = kg[0]; \
    *(short8v*)&Ks[(base + 8)  ^ sw] = kg[1]; \
    *(short8v*)&Ks[(base + 16) ^ sw] = kg[2]; \
    *(short8v*)&Ks[(base + 24) ^ sw] = kg[3]; \
    _Pragma("unroll") \
    for (int j = 0; j < 8; ++j) { \
        ushort4 w; \
        w.x = ((const unsigned short*)&vg[0])[j]; \
        w.y = ((const unsigned short*)&vg[1])[j]; \
        w.z = ((const unsigned short*)&vg[2])[j]; \
        w.w = ((const unsigned short*)&vg[3])[j]; \
        const int d = vd0 + j; \
        *(ushort4*)&Vt[(d * 64 + vk0) ^ ((d & 7) << 3)] = w; \
    } \
}

#define ACOMPUTE() { \
    f32x16 st0, st1; \
    _Pragma("unroll") for (int r = 0; r < 16; ++r) { st0[r] = 0.f; st1[r] = 0.f; } \
    _Pragma("unroll") \
    for (int s = 0; s < 4; ++s) { \
        short8v kf0 = *(const short8v*)&Ks[(l31 * 64 + s * 16 + lh * 8) ^ swr]; \
        st0 = __builtin_amdgcn_mfma_f32_32x32x16_bf16(kf0, qf[s], st0, 0, 0, 0); \
    } \
    _Pragma("unroll") \
    for (int s = 0; s < 4; ++s) { \
        short8v kf1 = *(const short8v*)&Ks[((32 + l31) * 64 + s * 16 + lh * 8) ^ swr]; \
        st1 = __builtin_amdgcn_mfma_f32_32x32x16_bf16(kf1, qf[s], st1, 0, 0, 0); \
    } \
    float rs = 0.f; \
    _Pragma("unroll") \
    for (int r = 0; r < 16; ++r) { \
        st0[r] = __builtin_exp2f(st0[r]); \
        rs += st0[r]; \
    } \
    _Pragma("unroll") \
    for (int r = 0; r < 16; ++r) { \
        st1[r] = __builtin_exp2f(st1[r]); \
        rs += st1[r]; \
    } \
    rs += __shfl_xor(rs, 32); \
    ll += rs; \
    unsigned int pk0[8], pk1[8], x0[8], x1[8]; \
    _Pragma("unroll") \
    for (int i2 = 0; i2 < 8; ++i2) { \
        pk0[i2] = cvtpk(st0[2 * i2], st0[2 * i2 + 1]); \
        pk1[i2] = cvtpk(st1[2 * i2], st1[2 * i2 + 1]); \
    } \
    _Pragma("unroll") \
    for (int i2 = 0; i2 < 8; ++i2) { \
        x0[i2] = (unsigned int)__shfl_xor((int)pk0[i2], 32); \
        x1[i2] = (unsigned int)__shfl_xor((int)pk1[i2], 32); \
    } \
    u32x4 pf[4]; \
    pf[0].x = hihalf ? x0[2] : pk0[0];  pf[0].y = hihalf ? x0[3] : pk0[1]; \
    pf[0].z = hihalf ? pk0[2] : x0[0];  pf[0].w = hihalf ? pk0[3] : x0[1]; \
    pf[1].x = hihalf ? x0[6] : pk0[4];  pf[1].y = hihalf ? x0[7] : pk0[5]; \
    pf[1].z = hihalf ? pk0[6] : x0[4];  pf[1].w = hihalf ? pk0[7] : x0[5]; \
    pf[2].x = hihalf ? x1[2] : pk1[0];  pf[2].y = hihalf ? x1[3] : pk1[1]; \
    pf[2].z = hihalf ? pk1[2] : x1[0];  pf[2].w = hihalf ? pk1[3] : x1[1]; \
    pf[3].x = hihalf ? x1[6] : pk1[4];  pf[3].y = hihalf ? x1[7] : pk1[5]; \
    pf[3].z = hihalf ? pk1[6] : x1[4];  pf[3].w = hihalf ? pk1[7] : x1[5]; \
    _Pragma("unroll") \
    for (int ks2 = 0; ks2 < 4; ++ks2) { \
        const short8v pfr = u2s(pf[ks2]); \
        const int keyoff = ks2 * 16 + lh * 8; \
        short8v vf0 = *(const short8v*)&Vt[(l31 * 64 + keyoff) ^ swr]; \
        ot0 = __builtin_amdgcn_mfma_f32_32x32x16_bf16(vf0, pfr, ot0, 0, 0, 0); \
        short8v vf1 = *(const short8v*)&Vt[((32 + l31) * 64 + keyoff) ^ swr]; \
        ot1 = __builtin_amdgcn_mfma_f32_32x32x16_bf16(vf1, pfr, ot1, 0, 0, 0); \
    } \
}

    // ---- software pipeline over 16 chunks (this block's 1024 keys) ----
    ALOAD(0);
    AWRITE();
    for (int i = 0; i < 15; ++i) {
        ALOAD(i + 1);        // in flight during compute of chunk i
        __syncthreads();     // writes of chunk i visible
        ACOMPUTE();          // chunk i
        __syncthreads();     // all reads of chunk i done
        AWRITE();            // chunk i+1 (loads landed during compute)
    }
    __syncthreads();
    ACOMPUTE();              // chunk 15
#undef ALOAD
#undef AWRITE
#undef ACOMPUTE

    // ---- accumulate partials: exactly 2 adds per address (ksplit 0/1) ----
    const int qrow = qrow0 + l31;
    float* dst = Obuf + (size_t)qrow * D_MODEL + h * 64;
#pragma unroll
    for (int r = 0; r < 16; ++r) {
        const int dloc = (r & 3) + 8 * (r >> 2) + 4 * lh;
        atomicAdd(&dst[dloc], ot0[r]);
        atomicAdd(&dst[32 + dloc], ot1[r]);
    }
    if (lh == 0) atomicAdd(&lbuf[qrow * N_HEADS + h], ll);
}

// ---------------------------------------------------------------------------
// Normalize + split: aoh/aol = split_bf(O / l).
// ---------------------------------------------------------------------------
__global__ __launch_bounds__(256) void norm_split_kernel(
    const float* __restrict__ Obuf, const float* __restrict__ lbuf,
    unsigned short* __restrict__ aoh, unsigned short* __restrict__ aol)
{
    const size_t e0 = ((size_t)blockIdx.x * 256 + threadIdx.x) * 8;
    const int row = (int)(e0 >> 10);
    const int col = (int)(e0 & 1023);
    const float il = 1.0f / lbuf[row * N_HEADS + (col >> 6)];
    float4 o0 = *(const float4*)(Obuf + e0);
    float4 o1 = *(const float4*)(Obuf + e0 + 4);
    ushort4 ha, la, hb, lb;
    unsigned short hh, lo;
    split_bf(o0.x * il, hh, lo); ha.x = hh; la.x = lo;
    split_bf(o0.y * il, hh, lo); ha.y = hh; la.y = lo;
    split_bf(o0.z * il, hh, lo); ha.z = hh; la.z = lo;
    split_bf(o0.w * il, hh, lo); ha.w = hh; la.w = lo;
    split_bf(o1.x * il, hh, lo); hb.x = hh; lb.x = lo;
    split_bf(o1.y * il, hh, lo); hb.y = hh; lb.y = lo;
    split_bf(o1.z * il, hh, lo); hb.z = hh; lb.z = lo;
    split_bf(o1.w * il, hh, lo); hb.w = hh; lb.w = lo;
    *(ushort4*)(aoh + e0)     = ha;
    *(ushort4*)(aoh + e0 + 4) = hb;
    *(ushort4*)(aol + e0)     = la;
    *(ushort4*)(aol + e0 + 4) = lb;
}

// ---------------------------------------------------------------------------
extern "C" void kernel_launch(void* const* d_in, const int* in_sizes, int n_in,
                              void* d_out, int out_size, void* d_ws, size_t ws_size,
                              hipStream_t stream) {
    (void)in_sizes; (void)n_in; (void)out_size; (void)ws_size;

    const float* x     = (const float*)d_in[0];
    const float* w_qkv = (const float*)d_in[1];
    const float* b_qkv = (const float*)d_in[2];
    const float* w_out = (const float*)d_in[3];
    const float* b_out = (const float*)d_in[4];
    float* out = (float*)d_out;

    // ws layout (bytes). wqkvT_h overlays Obuf (disjoint lifetimes:
    // wqkvT_h dead after GEMM1; Obuf zeroed/written only after GEMM1).
    char* ws = (char*)d_ws;
    unsigned short* qkv_bf  = (unsigned short*)(ws);                   // 25,165,824
    unsigned short* aoh     = (unsigned short*)(ws + 25165824);        //  8,388,608
    unsigned short* aol     = (unsigned short*)(ws + 33554432);        //  8,388,608
    float*          Obuf    = (float*)(ws + 41943040);                 // 16,777,216
    float*          lbuf    = (float*)(ws + 58720256);                 //    262,144
    unsigned short* wqkvT_h = (unsigned short*)(ws + 41943040);        //  6,291,456 (overlay)
    unsigned short* woutT_h = (unsigned short*)(ws + 58982400);        //  2,097,152
    unsigned short* woutT_l = (unsigned short*)(ws + 61079552);        //  2,097,152
    // end: 63,176,704 B

    // 1) weight prep
    splitT_kernel<<<dim3((D_MODEL / 64) * (3 * D_MODEL / 64)), 256, 0, stream>>>(
        w_qkv, wqkvT_h, (unsigned short*)nullptr, D_MODEL, 3 * D_MODEL, D_MODEL, 0);
    splitT_kernel<<<dim3((D_MODEL / 64) * (D_MODEL / 64)), 256, 0, stream>>>(
        w_out, woutT_h, woutT_l, D_MODEL, D_MODEL, 0, 1);

    // 2) QKV projection (1-term bf16)
    gemm_xw_kernel<<<dim3((NROWS / 128) * (3 * D_MODEL / 128)), 256, 0, stream>>>(
        x, wqkvT_h, b_qkv, qkv_bf, NROWS, 3 * D_MODEL, D_MODEL, D_MODEL);

    // 3) zero O/l accumulators (after GEMM1 — Obuf overlays wqkvT_h)
    {
        const int n4 = (16777216 + 262144) / 16;   // float4 count
        zero_kernel<<<dim3((n4 + 255) / 256), 256, 0, stream>>>((float4*)Obuf, n4);
    }

    // 4) flash attention, K-split x2, atomic partial accumulation
    attn_mfma_kernel<<<dim3(NBATCH * N_HEADS, SEQ / 64, 2), 128, 0, stream>>>(
        qkv_bf, Obuf, lbuf);

    // 5) normalize + hi/lo split
    norm_split_kernel<<<dim3(NROWS * D_MODEL / (256 * 8)), 256, 0, stream>>>(
        Obuf, lbuf, aoh, aol);

    // 6) output projection (3-term)
    gemm_ao_kernel<<<dim3((NROWS / 128) * (D_MODEL / 128)), 256, 0, stream>>>(
        aoh, aol, woutT_h, woutT_l, b_out, out, NROWS, D_MODEL, D_MODEL);
}

// Round 12
// 165.899 us; speedup vs baseline: 2.0985x; 2.0985x over previous
//
#include <hip/hip_runtime.h>
#include <hip/hip_bf16.h>
#include <math.h>

#define D_MODEL 1024
#define N_HEADS 16
#define D_HEAD  64
#define SEQ     2048
#define NBATCH  2
#define NROWS   (NBATCH * SEQ)      // 4096

#define C2F 0.18033688011112042f    // 0.125 * log2(e), folded into Q weights/bias

typedef __attribute__((ext_vector_type(8))) short short8v;        // 8 bf16
typedef __attribute__((ext_vector_type(4))) float f32x4;
typedef __attribute__((ext_vector_type(16))) float f32x16;
typedef __attribute__((ext_vector_type(4))) unsigned int u32x4;

__device__ __forceinline__ unsigned short f2bf(float x) {
    unsigned int u = __float_as_uint(x);
    return (unsigned short)((u + 0x7FFFu + ((u >> 16) & 1u)) >> 16);   // RNE
}
// truncation split: hi = top-16-bits of fp32, lo = RNE(x - hi)
__device__ __forceinline__ void split_bf(float x, unsigned short& hi, unsigned short& lo) {
    unsigned int u = __float_as_uint(x);
    unsigned int ht = u & 0xFFFF0000u;
    hi = (unsigned short)(ht >> 16);
    lo = f2bf(x - __uint_as_float(ht));
}
// packed RNE f32x2 -> bf16x2
__device__ __forceinline__ unsigned int cvtpk(float lo, float hi) {
    unsigned int r;
    asm("v_cvt_pk_bf16_f32 %0, %1, %2" : "=v"(r) : "v"(lo), "v"(hi));
    return r;
}
__device__ __forceinline__ short8v u2s(u32x4 v) {
    union { u32x4 u; short8v s; } c; c.u = v; return c.s;
}

// ---------------------------------------------------------------------------
// Weight transpose + split: W[K][N] fp32 -> Th[N][K] (+ Tl[N][K] if write_lo).
// Columns n < qcols pre-scaled by C2F. write_lo=0 -> Th is RNE-rounded.
// ---------------------------------------------------------------------------
__global__ __launch_bounds__(256) void splitT_kernel(
    const float* __restrict__ W, unsigned short* __restrict__ Th,
    unsigned short* __restrict__ Tl, int K, int N, int qcols, int write_lo)
{
    __shared__ float tile[64][68];
    const int tid = threadIdx.x;
    const int nbn = N >> 6;
    const int k0 = (blockIdx.x / nbn) << 6;
    const int n0 = (blockIdx.x % nbn) << 6;
    const int r  = tid >> 4;
    const int c4 = (tid & 15) * 4;

#pragma unroll
    for (int i = 0; i < 4; ++i) {
        float4 v = *(const float4*)(W + (size_t)(k0 + r + i * 16) * N + n0 + c4);
        *(float4*)&tile[r + i * 16][c4] = v;
    }
    __syncthreads();

    const int kl = (tid & 15) * 4;
#pragma unroll
    for (int i = 0; i < 4; ++i) {
        const int nl = (tid >> 4) + i * 16;
        const float sc = (n0 + nl < qcols) ? C2F : 1.0f;
        if (write_lo) {
            ushort4 h4, l4;
            unsigned short h, l;
            split_bf(tile[kl + 0][nl] * sc, h, l); h4.x = h; l4.x = l;
            split_bf(tile[kl + 1][nl] * sc, h, l); h4.y = h; l4.y = l;
            split_bf(tile[kl + 2][nl] * sc, h, l); h4.z = h; l4.z = l;
            split_bf(tile[kl + 3][nl] * sc, h, l); h4.w = h; l4.w = l;
            *(ushort4*)(Th + (size_t)(n0 + nl) * K + k0 + kl) = h4;
            *(ushort4*)(Tl + (size_t)(n0 + nl) * K + k0 + kl) = l4;
        } else {
            ushort4 h4;
            h4.x = f2bf(tile[kl + 0][nl] * sc);
            h4.y = f2bf(tile[kl + 1][nl] * sc);
            h4.z = f2bf(tile[kl + 2][nl] * sc);
            h4.w = f2bf(tile[kl + 3][nl] * sc);
            *(ushort4*)(Th + (size_t)(n0 + nl) * K + k0 + kl) = h4;
        }
    }
}

// ---------------------------------------------------------------------------
// GEMM1 (1-term bf16): qkv[M,N](bf16) = RNE_bf16(A) @ Bh[N,K]^T + bias.
// Software-pipelined (T14 rotation). Validated in R11: absmax unchanged.
// ---------------------------------------------------------------------------
#define ASTRIDE 40    // bf16 elems; 80B row stride

__global__ __launch_bounds__(256) void gemm_xw_kernel(
    const float* __restrict__ A,
    const unsigned short* __restrict__ Bth,
    const float* __restrict__ bias,
    unsigned short* __restrict__ C, int M, int N, int K, int qcols)
{
    __shared__ __align__(16) unsigned short Ab[128][ASTRIDE];
    __shared__ __align__(16) unsigned short Bh[128][ASTRIDE];

    const int tid  = threadIdx.x;
    const int wave = tid >> 6;
    const int lane = tid & 63;
    const int col  = lane & 15;
    const int q4   = lane >> 4;
    const int wm   = (wave >> 1) * 64;
    const int wn   = (wave & 1) * 64;

    const int nwg = gridDim.x;
    const int cpx = nwg >> 3;
    const int swz = (blockIdx.x & 7) * cpx + (blockIdx.x >> 3);
    const int nbn = N / 128;
    const int bm = (swz / nbn) * 128;
    const int bn = (swz % nbn) * 128;

    const int sr = tid >> 1;
    const int sq = (tid & 1) * 16;
    const float* aptr = A + (size_t)(bm + sr) * K + sq;
    const unsigned short* bhp = Bth + (size_t)(bn + sr) * K + sq;

    f32x4 acc[4][4];
#pragma unroll
    for (int i = 0; i < 4; ++i)
#pragma unroll
        for (int j = 0; j < 4; ++j) acc[i][j] = (f32x4){0.f, 0.f, 0.f, 0.f};

    float4 a0, a1, a2, a3;
    short8v b0h, b1h;

#define G1LOAD(k0) { \
    a0 = *(const float4*)(aptr + (k0)); \
    a1 = *(const float4*)(aptr + (k0) + 4); \
    a2 = *(const float4*)(aptr + (k0) + 8); \
    a3 = *(const float4*)(aptr + (k0) + 12); \
    b0h = *(const short8v*)(bhp + (k0)); \
    b1h = *(const short8v*)(bhp + (k0) + 8); \
}

#define G1WRITE() { \
    u32x4 p0, p1; \
    p0.x = cvtpk(a0.x, a0.y); p0.y = cvtpk(a0.z, a0.w); \
    p0.z = cvtpk(a1.x, a1.y); p0.w = cvtpk(a1.z, a1.w); \
    p1.x = cvtpk(a2.x, a2.y); p1.y = cvtpk(a2.z, a2.w); \
    p1.z = cvtpk(a3.x, a3.y); p1.w = cvtpk(a3.z, a3.w); \
    *(u32x4*)&Ab[sr][sq]     = p0; \
    *(u32x4*)&Ab[sr][sq + 8] = p1; \
    *(short8v*)&Bh[sr][sq]     = b0h; \
    *(short8v*)&Bh[sr][sq + 8] = b1h; \
}

#define G1COMP() { \
    short8v af[4]; \
    _Pragma("unroll") \
    for (int mt = 0; mt < 4; ++mt) \
        af[mt] = *(const short8v*)&Ab[wm + mt * 16 + col][q4 * 8]; \
    _Pragma("unroll") \
    for (int nt = 0; nt < 4; ++nt) { \
        short8v bhf = *(const short8v*)&Bh[wn + nt * 16 + col][q4 * 8]; \
        _Pragma("unroll") \
        for (int mt = 0; mt < 4; ++mt) \
            acc[mt][nt] = __builtin_amdgcn_mfma_f32_16x16x32_bf16(af[mt], bhf, acc[mt][nt], 0, 0, 0); \
    } \
}

    G1LOAD(0);
    G1WRITE();
    for (int k0 = 32; k0 < K; k0 += 32) {
        G1LOAD(k0);
        __syncthreads();
        G1COMP();
        __syncthreads();
        G1WRITE();
    }
    __syncthreads();
    G1COMP();
#undef G1LOAD
#undef G1WRITE
#undef G1COMP

    const float bscale = (bn < qcols) ? C2F : 1.0f;
    float bv[4];
#pragma unroll
    for (int nt = 0; nt < 4; ++nt) bv[nt] = bias[bn + wn + nt * 16 + col] * bscale;

#pragma unroll
    for (int mt = 0; mt < 4; ++mt)
#pragma unroll
        for (int r = 0; r < 4; ++r) {
            const int row = bm + wm + mt * 16 + q4 * 4 + r;
#pragma unroll
            for (int nt = 0; nt < 4; ++nt)
                C[(size_t)row * N + bn + wn + nt * 16 + col] = f2bf(acc[mt][nt][r] + bv[nt]);
        }
}

// ---------------------------------------------------------------------------
// GEMM2: out[M,N](fp32) = (Aoh+Aol)[M,K] @ (Bh+Bl)[N,K]^T + bias, 3-term.
// ---------------------------------------------------------------------------
__global__ __launch_bounds__(256) void gemm_ao_kernel(
    const unsigned short* __restrict__ Aoh,
    const unsigned short* __restrict__ Aol,
    const unsigned short* __restrict__ Bth,
    const unsigned short* __restrict__ Btl,
    const float* __restrict__ bias,
    float* __restrict__ C, int M, int N, int K)
{
    __shared__ __align__(16) unsigned short Ah[128][ASTRIDE];
    __shared__ __align__(16) unsigned short Al[128][ASTRIDE];
    __shared__ __align__(16) unsigned short Bh[128][ASTRIDE];
    __shared__ __align__(16) unsigned short Bl[128][ASTRIDE];

    const int tid  = threadIdx.x;
    const int wave = tid >> 6;
    const int lane = tid & 63;
    const int col  = lane & 15;
    const int q4   = lane >> 4;
    const int wm   = (wave >> 1) * 64;
    const int wn   = (wave & 1) * 64;

    const int nwg = gridDim.x;
    const int cpx = nwg >> 3;
    const int swz = (blockIdx.x & 7) * cpx + (blockIdx.x >> 3);
    const int nbn = N / 128;
    const int bm = (swz / nbn) * 128;
    const int bn = (swz % nbn) * 128;

    const int sr = tid >> 1;
    const int sq = (tid & 1) * 16;
    const unsigned short* ahp = Aoh + (size_t)(bm + sr) * K + sq;
    const unsigned short* alp = Aol + (size_t)(bm + sr) * K + sq;
    const unsigned short* bhp = Bth + (size_t)(bn + sr) * K + sq;
    const unsigned short* blp = Btl + (size_t)(bn + sr) * K + sq;

    f32x4 acc[4][4];
#pragma unroll
    for (int i = 0; i < 4; ++i)
#pragma unroll
        for (int j = 0; j < 4; ++j) acc[i][j] = (f32x4){0.f, 0.f, 0.f, 0.f};

    short8v a0h, a1h, a0l, a1l, b0h, b1h, b0l, b1l;

#define G2LOAD(k0) { \
    a0h = *(const short8v*)(ahp + (k0)); \
    a1h = *(const short8v*)(ahp + (k0) + 8); \
    a0l = *(const short8v*)(alp + (k0)); \
    a1l = *(const short8v*)(alp + (k0) + 8); \
    b0h = *(const short8v*)(bhp + (k0)); \
    b1h = *(const short8v*)(bhp + (k0) + 8); \
    b0l = *(const short8v*)(blp + (k0)); \
    b1l = *(const short8v*)(blp + (k0) + 8); \
}

#define G2WRITE() { \
    *(short8v*)&Ah[sr][sq]     = a0h; \
    *(short8v*)&Ah[sr][sq + 8] = a1h; \
    *(short8v*)&Al[sr][sq]     = a0l; \
    *(short8v*)&Al[sr][sq + 8] = a1l; \
    *(short8v*)&Bh[sr][sq]     = b0h; \
    *(short8v*)&Bh[sr][sq + 8] = b1h; \
    *(short8v*)&Bl[sr][sq]     = b0l; \
    *(short8v*)&Bl[sr][sq + 8] = b1l; \
}

#define G2COMP() { \
    short8v ahf[4], alf[4]; \
    _Pragma("unroll") \
    for (int mt = 0; mt < 4; ++mt) { \
        ahf[mt] = *(const short8v*)&Ah[wm + mt * 16 + col][q4 * 8]; \
        alf[mt] = *(const short8v*)&Al[wm + mt * 16 + col][q4 * 8]; \
    } \
    _Pragma("unroll") \
    for (int nt = 0; nt < 4; ++nt) { \
        short8v bhf = *(const short8v*)&Bh[wn + nt * 16 + col][q4 * 8]; \
        short8v blf = *(const short8v*)&Bl[wn + nt * 16 + col][q4 * 8]; \
        _Pragma("unroll") \
        for (int mt = 0; mt < 4; ++mt) { \
            acc[mt][nt] = __builtin_amdgcn_mfma_f32_16x16x32_bf16(ahf[mt], bhf, acc[mt][nt], 0, 0, 0); \
            acc[mt][nt] = __builtin_amdgcn_mfma_f32_16x16x32_bf16(alf[mt], bhf, acc[mt][nt], 0, 0, 0); \
            acc[mt][nt] = __builtin_amdgcn_mfma_f32_16x16x32_bf16(ahf[mt], blf, acc[mt][nt], 0, 0, 0); \
        } \
    } \
}

    G2LOAD(0);
    G2WRITE();
    for (int k0 = 32; k0 < K; k0 += 32) {
        G2LOAD(k0);
        __syncthreads();
        G2COMP();
        __syncthreads();
        G2WRITE();
    }
    __syncthreads();
    G2COMP();
#undef G2LOAD
#undef G2WRITE
#undef G2COMP

    float bv[4];
#pragma unroll
    for (int nt = 0; nt < 4; ++nt) bv[nt] = bias[bn + wn + nt * 16 + col];

#pragma unroll
    for (int mt = 0; mt < 4; ++mt)
#pragma unroll
        for (int r = 0; r < 4; ++r) {
            const int row = bm + wm + mt * 16 + q4 * 4 + r;
#pragma unroll
            for (int nt = 0; nt < 4; ++nt)
                C[(size_t)row * N + bn + wn + nt * 16 + col] = acc[mt][nt][r] + bv[nt];
        }
}

// ---------------------------------------------------------------------------
// MFMA flash attention — exact R10 version (best measured: 86 µs).
// Transposed-space 32x32x16, fixed-max softmax, T14 pipeline rotation,
// direct split_bf output. No K-split, no atomics.
// ---------------------------------------------------------------------------
__global__ __launch_bounds__(128) void attn_mfma_kernel(
    const unsigned short* __restrict__ qkv,
    unsigned short* __restrict__ aoh, unsigned short* __restrict__ aol)
{
    __shared__ __align__(16) unsigned short Ks[64 * 64];   // [key][dim] swizzled
    __shared__ __align__(16) unsigned short Vt[64 * 64];   // [dim][key] swizzled

    const int tid  = threadIdx.x;
    const int wave = tid >> 6;
    const int lane = tid & 63;
    const int l31  = lane & 31;
    const int lh   = lane >> 5;
    const bool hihalf = (lh != 0);

    const int bh = blockIdx.x;           // b*16 + h
    const int qt = blockIdx.y;           // 0..31
    const int b = bh >> 4;
    const int h = bh & 15;
    const int qrow0 = b * SEQ + qt * 64 + wave * 32;
    const int krow0 = b * SEQ;

    // Q fragments (B-operand), pre-scaled by C2F in GEMM1
    short8v qf[4];
    {
        const unsigned short* qsrc = qkv + (size_t)(qrow0 + l31) * (3 * D_MODEL) + h * 64 + lh * 8;
#pragma unroll
        for (int s = 0; s < 4; ++s)
            qf[s] = *(const short8v*)(qsrc + s * 16);
    }

    // staging indices (128 threads)
    const int krow  = tid >> 1;          // 0..63
    const int khalf = (tid & 1) * 32;    // elems (64 B half-row)
    const int vk0   = (tid & 15) * 4;    // 4 keys
    const int vd0   = (tid >> 4) * 8;    // 8 dims

    f32x16 ot0, ot1;
#pragma unroll
    for (int r = 0; r < 16; ++r) { ot0[r] = 0.f; ot1[r] = 0.f; }
    float ll = 0.f;

    short8v kg[4], vg[4];
    const int swr = (lane & 7) << 3;

#define ALOAD(c) { \
    const unsigned short* ksrc = qkv + (size_t)(krow0 + (c) * 64 + krow) * (3 * D_MODEL) \
                                 + D_MODEL + h * 64 + khalf; \
    kg[0] = ((const short8v*)ksrc)[0]; \
    kg[1] = ((const short8v*)ksrc)[1]; \
    kg[2] = ((const short8v*)ksrc)[2]; \
    kg[3] = ((const short8v*)ksrc)[3]; \
    _Pragma("unroll") \
    for (int i2 = 0; i2 < 4; ++i2) \
        vg[i2] = *(const short8v*)(qkv + (size_t)(krow0 + (c) * 64 + vk0 + i2) * (3 * D_MODEL) \
                                   + 2 * D_MODEL + h * 64 + vd0); \
}

#define AWRITE() { \
    const int base = krow * 64 + khalf; \
    const int sw = (krow & 7) << 3; \
    *(short8v*)&Ks[(base)      ^ sw] = kg[0]; \
    *(short8v*)&Ks[(base + 8)  ^ sw] = kg[1]; \
    *(short8v*)&Ks[(base + 16) ^ sw] = kg[2]; \
    *(short8v*)&Ks[(base + 24) ^ sw] = kg[3]; \
    _Pragma("unroll") \
    for (int j = 0; j < 8; ++j) { \
        ushort4 w; \
        w.x = ((const unsigned short*)&vg[0])[j]; \
        w.y = ((const unsigned short*)&vg[1])[j]; \
        w.z = ((const unsigned short*)&vg[2])[j]; \
        w.w = ((const unsigned short*)&vg[3])[j]; \
        const int d = vd0 + j; \
        *(ushort4*)&Vt[(d * 64 + vk0) ^ ((d & 7) << 3)] = w; \
    } \
}

#define ACOMPUTE() { \
    f32x16 st0, st1; \
    _Pragma("unroll") for (int r = 0; r < 16; ++r) { st0[r] = 0.f; st1[r] = 0.f; } \
    _Pragma("unroll") \
    for (int s = 0; s < 4; ++s) { \
        short8v kf0 = *(const short8v*)&Ks[(l31 * 64 + s * 16 + lh * 8) ^ swr]; \
        st0 = __builtin_amdgcn_mfma_f32_32x32x16_bf16(kf0, qf[s], st0, 0, 0, 0); \
    } \
    _Pragma("unroll") \
    for (int s = 0; s < 4; ++s) { \
        short8v kf1 = *(const short8v*)&Ks[((32 + l31) * 64 + s * 16 + lh * 8) ^ swr]; \
        st1 = __builtin_amdgcn_mfma_f32_32x32x16_bf16(kf1, qf[s], st1, 0, 0, 0); \
    } \
    float rs = 0.f; \
    _Pragma("unroll") \
    for (int r = 0; r < 16; ++r) { \
        st0[r] = __builtin_exp2f(st0[r]); \
        rs += st0[r]; \
    } \
    _Pragma("unroll") \
    for (int r = 0; r < 16; ++r) { \
        st1[r] = __builtin_exp2f(st1[r]); \
        rs += st1[r]; \
    } \
    rs += __shfl_xor(rs, 32); \
    ll += rs; \
    unsigned int pk0[8], pk1[8], x0[8], x1[8]; \
    _Pragma("unroll") \
    for (int i2 = 0; i2 < 8; ++i2) { \
        pk0[i2] = cvtpk(st0[2 * i2], st0[2 * i2 + 1]); \
        pk1[i2] = cvtpk(st1[2 * i2], st1[2 * i2 + 1]); \
    } \
    _Pragma("unroll") \
    for (int i2 = 0; i2 < 8; ++i2) { \
        x0[i2] = (unsigned int)__shfl_xor((int)pk0[i2], 32); \
        x1[i2] = (unsigned int)__shfl_xor((int)pk1[i2], 32); \
    } \
    u32x4 pf[4]; \
    pf[0].x = hihalf ? x0[2] : pk0[0];  pf[0].y = hihalf ? x0[3] : pk0[1]; \
    pf[0].z = hihalf ? pk0[2] : x0[0];  pf[0].w = hihalf ? pk0[3] : x0[1]; \
    pf[1].x = hihalf ? x0[6] : pk0[4];  pf[1].y = hihalf ? x0[7] : pk0[5]; \
    pf[1].z = hihalf ? pk0[6] : x0[4];  pf[1].w = hihalf ? pk0[7] : x0[5]; \
    pf[2].x = hihalf ? x1[2] : pk1[0];  pf[2].y = hihalf ? x1[3] : pk1[1]; \
    pf[2].z = hihalf ? pk1[2] : x1[0];  pf[2].w = hihalf ? pk1[3] : x1[1]; \
    pf[3].x = hihalf ? x1[6] : pk1[4];  pf[3].y = hihalf ? x1[7] : pk1[5]; \
    pf[3].z = hihalf ? pk1[6] : x1[4];  pf[3].w = hihalf ? pk1[7] : x1[5]; \
    _Pragma("unroll") \
    for (int ks2 = 0; ks2 < 4; ++ks2) { \
        const short8v pfr = u2s(pf[ks2]); \
        const int keyoff = ks2 * 16 + lh * 8; \
        short8v vf0 = *(const short8v*)&Vt[(l31 * 64 + keyoff) ^ swr]; \
        ot0 = __builtin_amdgcn_mfma_f32_32x32x16_bf16(vf0, pfr, ot0, 0, 0, 0); \
        short8v vf1 = *(const short8v*)&Vt[((32 + l31) * 64 + keyoff) ^ swr]; \
        ot1 = __builtin_amdgcn_mfma_f32_32x32x16_bf16(vf1, pfr, ot1, 0, 0, 0); \
    } \
}

    // ---- software pipeline ----
    ALOAD(0);
    AWRITE();
    for (int i = 0; i < 31; ++i) {
        ALOAD(i + 1);        // in flight during compute of chunk i
        __syncthreads();     // writes of chunk i visible
        ACOMPUTE();          // chunk i
        __syncthreads();     // all reads of chunk i done
        AWRITE();            // chunk i+1 (loads landed during compute)
    }
    __syncthreads();
    ACOMPUTE();              // chunk 31
#undef ALOAD
#undef AWRITE
#undef ACOMPUTE

    // ---- finalize: lane holds q = l31; O^T rows are dims ----
    const float il = 1.0f / ll;
    const int qrow = qrow0 + l31;
    unsigned short* dh = aoh + (size_t)qrow * D_MODEL + h * 64;
    unsigned short* dl = aol + (size_t)qrow * D_MODEL + h * 64;
#pragma unroll
    for (int r = 0; r < 16; ++r) {
        const int dloc = (r & 3) + 8 * (r >> 2) + 4 * lh;
        unsigned short hh, lo2;
        split_bf(ot0[r] * il, hh, lo2);
        dh[dloc] = hh; dl[dloc] = lo2;
        split_bf(ot1[r] * il, hh, lo2);
        dh[32 + dloc] = hh; dl[32 + dloc] = lo2;
    }
}

// ---------------------------------------------------------------------------
extern "C" void kernel_launch(void* const* d_in, const int* in_sizes, int n_in,
                              void* d_out, int out_size, void* d_ws, size_t ws_size,
                              hipStream_t stream) {
    (void)in_sizes; (void)n_in; (void)out_size; (void)ws_size;

    const float* x     = (const float*)d_in[0];
    const float* w_qkv = (const float*)d_in[1];
    const float* b_qkv = (const float*)d_in[2];
    const float* w_out = (const float*)d_in[3];
    const float* b_out = (const float*)d_in[4];
    float* out = (float*)d_out;

    char* ws = (char*)d_ws;
    unsigned short* qkv_bf  = (unsigned short*)(ws);                   // 25,165,824
    unsigned short* aoh     = (unsigned short*)(ws + 25165824);        //  8,388,608
    unsigned short* aol     = (unsigned short*)(ws + 33554432);        //  8,388,608
    unsigned short* wqkvT_h = (unsigned short*)(ws + 41943040);        //  6,291,456
    unsigned short* woutT_h = (unsigned short*)(ws + 48234496);        //  2,097,152
    unsigned short* woutT_l = (unsigned short*)(ws + 50331648);        //  2,097,152
    // end: 52,428,800 B

    // 1) weight prep: qkv weights RNE (1-term GEMM1), out weights hi/lo split
    splitT_kernel<<<dim3((D_MODEL / 64) * (3 * D_MODEL / 64)), 256, 0, stream>>>(
        w_qkv, wqkvT_h, (unsigned short*)nullptr, D_MODEL, 3 * D_MODEL, D_MODEL, 0);
    splitT_kernel<<<dim3((D_MODEL / 64) * (D_MODEL / 64)), 256, 0, stream>>>(
        w_out, woutT_h, woutT_l, D_MODEL, D_MODEL, 0, 1);

    // 2) QKV projection (1-term bf16)
    gemm_xw_kernel<<<dim3((NROWS / 128) * (3 * D_MODEL / 128)), 256, 0, stream>>>(
        x, wqkvT_h, b_qkv, qkv_bf, NROWS, 3 * D_MODEL, D_MODEL, D_MODEL);

    // 3) flash attention (R10 version, direct split output)
    attn_mfma_kernel<<<dim3(NBATCH * N_HEADS, SEQ / 64), 128, 0, stream>>>(qkv_bf, aoh, aol);

    // 4) output projection (3-term)
    gemm_ao_kernel<<<dim3((NROWS / 128) * (D_MODEL / 128)), 256, 0, stream>>>(
        aoh, aol, woutT_h, woutT_l, b_out, out, NROWS, D_MODEL, D_MODEL);
}